// Round 3
// baseline (474.288 us; speedup 1.0000x reference)
//
#include <hip/hip_runtime.h>
#include <hip/hip_fp16.h>
#include <math.h>

#define HDIM 1024
#define NEXP 8
#define FDIM 4096
#define CAP 512

typedef _Float16 half8 __attribute__((ext_vector_type(8)));
typedef float floatx4 __attribute__((ext_vector_type(4)));

// async global->LDS, 16B per lane; lds dest = wave-uniform base + lane*16
__device__ __forceinline__ void glds16(const __half* g, __half* ldsbase) {
    __builtin_amdgcn_global_load_lds(
        (const __attribute__((address_space(1))) void*)g,
        (__attribute__((address_space(3))) void*)ldsbase,
        16, 0, 0);
}

// tanh-form GELU: v - v/(exp2(2.3022082*(v+0.044715 v^3))+1); |err vs erf-gelu| ~1e-3
__device__ __forceinline__ float fast_gelu(float v) {
    float t = 2.3022082f * v * (1.f + 0.044715f * v * v);
    return v - v * __builtin_amdgcn_rcpf(__builtin_amdgcn_exp2f(t) + 1.f);
}

// ---------------- per-wave gate for one token t ----------------
__device__ __forceinline__
void dev_gate(const float* __restrict__ x, const float* __restrict__ Wg,
              const float* __restrict__ bg,
              float* __restrict__ wgt, int* __restrict__ src, int* __restrict__ ord,
              int t, int lane) {
    const float* xr = x + (size_t)t * HDIM;
    float acc[NEXP];
#pragma unroll
    for (int e = 0; e < NEXP; e++) acc[e] = 0.f;
    for (int i = lane; i < HDIM; i += 64) {
        float xv = xr[i];
        const float* wr = Wg + (size_t)i * NEXP;
#pragma unroll
        for (int e = 0; e < NEXP; e++) acc[e] += xv * wr[e];
    }
#pragma unroll
    for (int e = 0; e < NEXP; e++) {
        float v = acc[e];
#pragma unroll
        for (int off = 1; off < 64; off <<= 1) v += __shfl_xor(v, off, 64);
        acc[e] = v;
    }
    if (lane == 0) {
        float p[NEXP];
        float mx = -1e30f;
#pragma unroll
        for (int e = 0; e < NEXP; e++) { acc[e] += bg[e]; mx = fmaxf(mx, acc[e]); }
        float s = 0.f;
#pragma unroll
        for (int e = 0; e < NEXP; e++) { p[e] = expf(acc[e] - mx); s += p[e]; }
        float inv = 1.f / s;
        float s2 = 0.f;
#pragma unroll
        for (int e = 0; e < NEXP; e++) { p[e] *= inv; s2 += p[e]; }
        float norm = 1.f / (s2 + 1e-9f);
        int used = 0;
        // selection sort descending; strict > ascending scan == jax top_k tie rule
        for (int r = 0; r < 8; r++) {
            int best = 0; float bv = -1.f;
            for (int e = 0; e < NEXP; e++) {
                if (!((used >> e) & 1) && p[e] > bv) { bv = p[e]; best = e; }
            }
            used |= 1 << best;
            wgt[best * CAP + t] = p[best] * norm;
            src[best * CAP + t] = 4 * t + (r >> 1);   // faithful tok = f//K bug
            ord[t * 8 + r] = best;
        }
    }
}

// ---------------- 64x64 tile transpose+convert: W[R][C] fp32 -> WT[C][R] fp16 ----------------
__device__ __forceinline__
void dev_transpose(const float* __restrict__ We, __half* __restrict__ WTe,
                   int R, int C, int tr, int tc, float (*tile)[65]) {
    const int tid = threadIdx.x;
    {
        const int c0 = (tid & 15) * 4;
        const int r0 = tid >> 4;
#pragma unroll
        for (int it = 0; it < 4; it++) {
            const int r = r0 + it * 16;
            float4 v = *(const float4*)(We + (size_t)(tr + r) * C + tc + c0);
            tile[r][c0] = v.x; tile[r][c0 + 1] = v.y; tile[r][c0 + 2] = v.z; tile[r][c0 + 3] = v.w;
        }
    }
    __syncthreads();
    {
        const int cc = tid >> 2;
        const int rr0 = (tid & 3) * 16;
        __half h[16];
#pragma unroll
        for (int i = 0; i < 16; i++) h[i] = __float2half(tile[rr0 + i][cc]);
        __half* dst = WTe + (size_t)(tc + cc) * R + tr + rr0;
        *(int4*)dst = *(int4*)h;
        *(int4*)(dst + 8) = *(int4*)(h + 8);
    }
}

// ---------------- m97-style GEMM core: 128x128 tile, 4 waves 2x2, 4x4 16x16x32 frags ----------------
// A: [.][512][Kd] fp16 k-contig; BT: [.][Nd][Kd] fp16 k-contig.
template <int Kd, int Nd, bool GELU, int KSPLIT>
__device__ __forceinline__
void dev_gemm(const __half* __restrict__ A, const __half* __restrict__ BT,
              const float* __restrict__ bias, void* __restrict__ Cout,
              int e, int ks, int mBase, int nBase, __half* As, __half* Bs) {
    const int tid = threadIdx.x;
    const int lane = tid & 63;
    const int wu = __builtin_amdgcn_readfirstlane(tid >> 6);
    const int wm = wu >> 1, wn = wu & 1;
    const int quad = lane >> 4, l15 = lane & 15;
    const int kLen = Kd / KSPLIT;

    const __half* Ae = A + ((size_t)e * 512 + mBase) * Kd + (size_t)ks * kLen;
    const __half* Be = BT + ((size_t)e * Nd + nBase) * Kd + (size_t)ks * kLen;

    const int srow = lane >> 2;          // 0..15
    const int scol = (lane & 3) * 8;     // halves

    floatx4 acc[4][4] = {};

    for (int k0 = 0; k0 < kLen; k0 += 32) {
        __syncthreads();   // prior iteration's ds_reads complete before overwrite
        {
            const __half* ga = Ae + (size_t)(wu * 32 + srow) * Kd + k0 + scol;
            const __half* gb = Be + (size_t)(wu * 32 + srow) * Kd + k0 + scol;
            glds16(ga,                    As + (wu * 32) * 32);
            glds16(ga + (size_t)16 * Kd,  As + (wu * 32 + 16) * 32);
            glds16(gb,                    Bs + (wu * 32) * 32);
            glds16(gb + (size_t)16 * Kd,  Bs + (wu * 32 + 16) * 32);
        }
        __syncthreads();
        half8 af[4], bf[4];
#pragma unroll
        for (int i = 0; i < 4; i++) {
            af[i] = *(const half8*)&As[(wm * 64 + i * 16 + l15) * 32 + quad * 8];
            bf[i] = *(const half8*)&Bs[(wn * 64 + i * 16 + l15) * 32 + quad * 8];
        }
#pragma unroll
        for (int mi = 0; mi < 4; mi++)
#pragma unroll
            for (int ni = 0; ni < 4; ni++)
                acc[mi][ni] = __builtin_amdgcn_mfma_f32_16x16x32_f16(af[mi], bf[ni], acc[mi][ni], 0, 0, 0);
    }

    // epilogue: C[row][col], row=(lane>>4)*4+r, col=lane&15 (m89-verified mapping)
    const float* be = bias + (size_t)e * Nd + nBase;
    if (GELU) {
        __half* C = (__half*)Cout + ((size_t)e * 512 + mBase) * Nd + nBase;
#pragma unroll
        for (int mi = 0; mi < 4; mi++) {
#pragma unroll
            for (int ni = 0; ni < 4; ni++) {
                const int col = wn * 64 + ni * 16 + l15;
                const float b = be[col];
#pragma unroll
                for (int r = 0; r < 4; r++) {
                    const int row = wm * 64 + mi * 16 + quad * 4 + r;
                    C[(size_t)row * Nd + col] = __float2half(fast_gelu(acc[mi][ni][r] + b));
                }
            }
        }
    } else {
        float* C = (float*)Cout + (((size_t)ks * NEXP + e) * 512 + mBase) * Nd + nBase;
#pragma unroll
        for (int mi = 0; mi < 4; mi++) {
#pragma unroll
            for (int ni = 0; ni < 4; ni++) {
                const int col = wn * 64 + ni * 16 + l15;
                const float b = (ks == 0) ? be[col] : 0.f;
#pragma unroll
                for (int r = 0; r < 4; r++) {
                    const int row = wm * 64 + mi * 16 + quad * 4 + r;
                    C[(size_t)row * Nd + col] = acc[mi][ni][r] + b;
                }
            }
        }
    }
}

// ---------------- fused: gate (128 blocks) || transpose W1 (8192 blocks) ----------------
__global__ __launch_bounds__(256)
void fused_gate_tw1(const float* __restrict__ x, const float* __restrict__ Wg,
                    const float* __restrict__ bg,
                    float* __restrict__ wgt, int* __restrict__ src, int* __restrict__ ord,
                    const float* __restrict__ W1, __half* __restrict__ W1T) {
    __shared__ __align__(16) float tile[64][65];
    const int bx = blockIdx.x;
    if (bx < 128) {
        const int t = bx * 4 + (threadIdx.x >> 6);
        dev_gate(x, Wg, bg, wgt, src, ord, t, threadIdx.x & 63);
    } else {
        const int b = bx - 128;
        const int e = b >> 10, rem = b & 1023;
        // W1: R=HDIM rows, C=FDIM cols -> 16 row-tiles x 64 col-tiles
        const int tr = (rem >> 6) * 64, tc = (rem & 63) * 64;
        dev_transpose(W1 + (size_t)e * HDIM * FDIM, W1T + (size_t)e * HDIM * FDIM,
                      HDIM, FDIM, tr, tc, tile);
    }
}

// ---------------- fused: GEMM1 (1024 blocks) || transpose W2 (8192 blocks), 1:1 interleaved head ----------------
__global__ __launch_bounds__(256, 4)
void fused_gemm1_tw2(const __half* __restrict__ buf, const __half* __restrict__ W1T,
                     const float* __restrict__ b1, __half* __restrict__ hmid,
                     const float* __restrict__ W2, __half* __restrict__ W2T) {
    __shared__ __align__(16) char smem[16640];   // max(2*128*32*2, 64*65*4)
    const int bx = blockIdx.x;
    int g = -1, tIdx = -1;
    if (bx < 2048) { if ((bx & 1) == 0) g = bx >> 1; else tIdx = bx >> 1; }
    else tIdx = bx - 1024;
    if (g >= 0) {
        const int e = g >> 7, r = g & 127;
        dev_gemm<HDIM, FDIM, true, 1>(buf, W1T, b1, hmid, e, 0, (r >> 5) * 128, (r & 31) * 128,
                                      (__half*)smem, (__half*)smem + 128 * 32);
    } else {
        const int e = tIdx >> 10, rem = tIdx & 1023;
        // W2: R=FDIM rows, C=HDIM cols -> 64 row-tiles x 16 col-tiles
        const int tr = (rem >> 4) * 64, tc = (rem & 15) * 64;
        dev_transpose(W2 + (size_t)e * FDIM * HDIM, W2T + (size_t)e * FDIM * HDIM,
                      FDIM, HDIM, tr, tc, (float (*)[65])smem);
    }
}

// ---------------- dispatch: buf[e][t][:] = w * x[src] (fp16) ----------------
__global__ __launch_bounds__(256)
void moe_dispatch_kernel(const float* __restrict__ x, const float* __restrict__ wgt,
                         const int* __restrict__ src, __half* __restrict__ buf) {
    const int row = blockIdx.x;
    const int tid = threadIdx.x;
    const float w = wgt[row];
    const int s = src[row];
    float4 v = ((const float4*)(x + (size_t)s * HDIM))[tid];
    __half2 h0 = __floats2half2_rn(v.x * w, v.y * w);
    __half2 h1 = __floats2half2_rn(v.z * w, v.w * w);
    __half2* o = (__half2*)(buf + (size_t)row * HDIM);
    o[tid * 2]     = h0;
    o[tid * 2 + 1] = h1;
}

// ---------------- GEMM2: K=4096, KSPLIT=4 partials ----------------
__global__ __launch_bounds__(256, 4)
void moe_gemm2_kernel(const __half* __restrict__ hmid, const __half* __restrict__ W2T,
                      const float* __restrict__ b2, float* __restrict__ outb) {
    __shared__ __align__(16) __half As[128 * 32];
    __shared__ __align__(16) __half Bs[128 * 32];
    const int e = blockIdx.z >> 2, ks = blockIdx.z & 3;
    dev_gemm<FDIM, HDIM, false, 4>(hmid, W2T, b2, outb, e, ks,
                                   blockIdx.y * 128, blockIdx.x * 128, As, Bs);
}

// ---------------- combine: sum 2 experts x 4 K-partials; zero tail; loss=0 ----------------
__global__ __launch_bounds__(256)
void moe_combine_kernel(const float* __restrict__ outb, const int* __restrict__ ord,
                        float* __restrict__ y) {
    const int j = blockIdx.x;
    const int tid = threadIdx.x;
    float4* yo = (float4*)(y + (size_t)j * HDIM);
    if (j >= 2048) {
        yo[tid] = float4{0.f, 0.f, 0.f, 0.f};
        if (j == 2048 && tid == 0) y[(size_t)8192 * HDIM] = 0.f;  // aux loss exactly 0 (em all-ones)
        return;
    }
    const int t = j >> 2, q = j & 3;
    const int e1 = ord[t * 8 + 2 * q];
    const int e2 = ord[t * 8 + 2 * q + 1];
    const size_t PSTR = (size_t)NEXP * CAP * HDIM;
    float4 s = {0.f, 0.f, 0.f, 0.f};
#pragma unroll
    for (int p = 0; p < 4; p++) {
        float4 a = ((const float4*)(outb + p * PSTR + ((size_t)e1 * CAP + t) * HDIM))[tid];
        float4 b = ((const float4*)(outb + p * PSTR + ((size_t)e2 * CAP + t) * HDIM))[tid];
        s.x += a.x + b.x; s.y += a.y + b.y; s.z += a.z + b.z; s.w += a.w + b.w;
    }
    yo[tid] = s;
}

extern "C" void kernel_launch(void* const* d_in, const int* in_sizes, int n_in,
                              void* d_out, int out_size, void* d_ws, size_t ws_size,
                              hipStream_t stream) {
    const float* x  = (const float*)d_in[0];
    const float* Wg = (const float*)d_in[1];
    const float* bg = (const float*)d_in[2];
    const float* W1 = (const float*)d_in[3];
    const float* b1 = (const float*)d_in[4];
    const float* W2 = (const float*)d_in[5];
    const float* b2 = (const float*)d_in[6];
    float* out = (float*)d_out;

    char* ws = (char*)d_ws;
    __half* buf  = (__half*)(ws);                   // 8 MB : [E][512][H] fp16
    __half* hmid = (__half*)(ws + (8ull  << 20));   // 32 MB: [E][512][F] fp16
    __half* W1T  = (__half*)(ws + (40ull << 20));   // 64 MB: [E][F][H] fp16 (dead after GEMM1)
    float*  outb = (float*)(ws + (40ull << 20));    // 64 MB: 4 partials [E][512][H] (reuses W1T)
    __half* W2T  = (__half*)(ws + (104ull << 20));  // 64 MB: [E][H][F] fp16
    float*  wgt  = (float*)(ws + (168ull << 20));
    int*    src  = (int*)  (ws + (168ull << 20) + 16384);
    int*    ord  = (int*)  (ws + (168ull << 20) + 32768);

    fused_gate_tw1<<<128 + 8192, 256, 0, stream>>>(x, Wg, bg, wgt, src, ord, W1, W1T);
    moe_dispatch_kernel<<<NEXP * CAP, 256, 0, stream>>>(x, wgt, src, buf);
    fused_gemm1_tw2<<<1024 + 8192, 256, 0, stream>>>(buf, W1T, b1, hmid, W2, W2T);
    moe_gemm2_kernel<<<dim3(HDIM / 128, 4, NEXP * 4), 256, 0, stream>>>(hmid, W2T, b2, outb);
    moe_combine_kernel<<<8192, 256, 0, stream>>>(outb, ord, out);
}